// Round 16
// baseline (177.575 us; speedup 1.0000x reference)
//
#include <hip/hip_runtime.h>

// ---------------------------------------------------------------------------
// UNetBlock1D — bf16 MFMA, round 16.
// B=16, CIN=256, COUT=512, L=1024, K=3, HEADS=8 (ch=64), GROUPS=32.
//
// Round-16 change: K=1 convs (qkv, proj) use BK=128 — two 64-ci chunks
// staged per round into a 64KB single buffer (still 2 blocks/CU), 64 MFMAs
// between barriers instead of 32. Halves barrier-drain count; deeper gload
// burst. K=3 convs and attention unchanged (round-12/15 validated).
// ---------------------------------------------------------------------------

typedef float f32x4 __attribute__((ext_vector_type(4)));
typedef float f32x16 __attribute__((ext_vector_type(16)));
typedef short short8 __attribute__((ext_vector_type(8)));

__device__ __forceinline__ unsigned short f2bf(float f) {
  union { float f; unsigned u; } v; v.f = f;
  return (unsigned short)((v.u + 0x7FFFu + ((v.u >> 16) & 1u)) >> 16);
}
__device__ __forceinline__ float bf2f(unsigned short h) {
  union { unsigned u; float f; } v; v.u = ((unsigned)h) << 16;
  return v.f;
}

__device__ __forceinline__ float fexp2(float x) {
  float r;
  asm("v_exp_f32 %0, %1" : "=v"(r) : "v"(x));
  return r;
}

__device__ __forceinline__ void gload_lds16(const void* g, void* l) {
  __builtin_amdgcn_global_load_lds(
      (const __attribute__((address_space(1))) unsigned int*)g,
      (__attribute__((address_space(3))) unsigned int*)l, 16, 0, 0);
}

// cross-half (lane ^ 32) combine via v_permlane32_swap_b32 (VALU)
__device__ __forceinline__ float swap_add(float x) {
  float a = x, b = x;
  asm("v_permlane32_swap_b32 %0, %1" : "+v"(a), "+v"(b));
  return a + b;
}

// pack 8 per-lane P values into the PV B-fragment short8 via cvt_pk + swap
__device__ __forceinline__ short8 pack8(float a0, float a1, float a2, float a3,
                                        float a4, float a5, float a6, float a7) {
  unsigned x0, x1, x2, x3;
  asm("v_cvt_pk_bf16_f32 %0, %1, %2" : "=v"(x0) : "v"(a0), "v"(a1));
  asm("v_cvt_pk_bf16_f32 %0, %1, %2" : "=v"(x1) : "v"(a2), "v"(a3));
  asm("v_cvt_pk_bf16_f32 %0, %1, %2" : "=v"(x2) : "v"(a4), "v"(a5));
  asm("v_cvt_pk_bf16_f32 %0, %1, %2" : "=v"(x3) : "v"(a6), "v"(a7));
  asm("v_permlane32_swap_b32 %0, %1" : "+v"(x0), "+v"(x2));
  asm("v_permlane32_swap_b32 %0, %1" : "+v"(x1), "+v"(x3));
  union { unsigned u[4]; short8 s; } r;
  r.u[0] = x0; r.u[1] = x1; r.u[2] = x2; r.u[3] = x3;
  return r.s;
}
#define PACK8(V, B) pack8(V[B+0], V[B+1], V[B+2], V[B+3], V[B+4], V[B+5], V[B+6], V[B+7])

// ---------------- merged weight prep + gn0 stats ----------------
// blocks [0,9216): weight conversion; [9216,9728): gn0 stats (CPG=8) + pads.
__global__ __launch_bounds__(256) void prep_stats(
    const float* __restrict__ c0w, const float* __restrict__ c1w,
    const float* __restrict__ skw, const float* __restrict__ qw,
    const float* __restrict__ pw,
    unsigned short* __restrict__ WT0, unsigned short* __restrict__ WT1,
    unsigned short* __restrict__ WSK, unsigned short* __restrict__ WQ,
    unsigned short* __restrict__ WP,
    const float* __restrict__ x, float2* __restrict__ mr,
    unsigned short* __restrict__ outT) {
  __shared__ float2 red[4];
  const int t = threadIdx.x;
  if (blockIdx.x >= 9216) {
    const int blk = blockIdx.x - 9216;
    const int g = blk & 31;
    const int bb = blk >> 5;
    const size_t base = ((size_t)bb * 256 + g * 8) * 1024;
    float s = 0.f, ss = 0.f;
#pragma unroll
    for (int i = t * 4; i < 8192; i += 1024) {
      const float4 v = *(const float4*)(x + base + i);
      s += (v.x + v.y) + (v.z + v.w);
      ss += (v.x * v.x + v.y * v.y) + (v.z * v.z + v.w * v.w);
    }
#pragma unroll
    for (int off = 32; off; off >>= 1) {
      s += __shfl_down(s, off);
      ss += __shfl_down(ss, off);
    }
    if ((t & 63) == 0) red[t >> 6] = make_float2(s, ss);
    __syncthreads();
    const float2 r0 = red[0], r1 = red[1], r2 = red[2], r3 = red[3];
    const float tots = (r0.x + r1.x) + (r2.x + r3.x);
    const float totss = (r0.y + r1.y) + (r2.y + r3.y);
    const float mean = tots * (1.f / 8192.f);
    const float var = totss * (1.f / 8192.f) - mean * mean;
    if (t == 0) mr[bb * 32 + g] = make_float2(mean, rsqrtf(var + 1e-5f));
    unsigned short* ob = outT + (size_t)bb * 1026 * 256 + g * 8;
    if (t < 8) {
      ob[t] = 0;
      ob[(size_t)1025 * 256 + t] = 0;
    }
    return;
  }
  int idx = blockIdx.x * 256 + t;
  if (idx < 393216) {        // WT0[kk][co][ci] <- c0w (512,256,3)
    const int ci = idx & 255; const int rem = idx >> 8;
    const int co = rem & 511; const int kk = rem >> 9;
    WT0[idx] = f2bf(c0w[((size_t)co * 256 + ci) * 3 + kk]); return;
  }
  idx -= 393216;
  if (idx < 786432) {        // WT1[kk][co][ci] <- c1w (512,512,3)
    const int ci = idx & 511; const int rem = idx >> 9;
    const int co = rem & 511; const int kk = rem >> 9;
    WT1[idx] = f2bf(c1w[((size_t)co * 512 + ci) * 3 + kk]); return;
  }
  idx -= 786432;
  if (idx < 131072) { WSK[idx] = f2bf(skw[idx]); return; }
  idx -= 131072;
  if (idx < 786432) {        // WQ s-major permuted
    const int ci = idx & 511; const int m = idx >> 9;
    const int s = m >> 9, rem = m & 511, h = rem >> 6, c = rem & 63;
    WQ[idx] = f2bf(qw[((size_t)(h * 192 + c * 3 + s) * 512) + ci]); return;
  }
  idx -= 786432;
  WP[idx] = f2bf(pw[idx]);
}

// ---------------- norm (+SiLU) + transpose, LDS-tiled, coalesced ------------
template<int MODE, bool SILU, int C, bool PADZ, bool RAW, bool IN16>
__global__ __launch_bounds__(256) void nt_kernel(
    const float* __restrict__ in, const float2* __restrict__ st,
    const float* __restrict__ gw, const float* __restrict__ gb,
    unsigned short* __restrict__ outT, unsigned short* __restrict__ rawT) {
  constexpr int CPG = C / 32;
  __shared__ float ls[64][65];
  __shared__ unsigned short lsr[RAW ? 64 : 1][72];
  __shared__ float2 gstat[4];
  const int b = blockIdx.z, c0 = blockIdx.y * 64, l0 = blockIdx.x * 64;
  const int t = threadIdx.x;
  if (MODE == 2) {
    if (t < 4) {
      const int g = (c0 >> 4) + t;
      const float2* p = st + (((size_t)b * 4 + (g >> 3)) * 8 + (g & 7)) * 8;
      float s = 0.f, ss = 0.f;
#pragma unroll
      for (int i = 0; i < 8; ++i) { s += p[i].x; ss += p[i].y; }
      const float mean = s * (1.f / 16384.f);
      const float var = ss * (1.f / 16384.f) - mean * mean;
      gstat[t] = make_float2(mean, rsqrtf(var + 1e-5f));
    }
    __syncthreads();
  }
  const int lw = (t & 15) * 4;
  const int cr = t >> 4;
#pragma unroll
  for (int p = 0; p < 4; ++p) {
    const int c = p * 16 + cr;
    const int cc = c0 + c;
    float sc = 1.f, bi = 0.f;
    if (MODE == 1) {
      const float2 ms = st[b * 32 + cc / CPG];
      sc = gw[cc] * ms.y;
      bi = gb[cc] - ms.x * sc;
    } else if (MODE == 2) {
      const float2 ms = gstat[c >> 4];
      sc = gw[cc] * ms.y;
      bi = gb[cc] - ms.x * sc;
    }
    float4 v;
    if (IN16) {
      const ushort4 u4 = *(const ushort4*)((const unsigned short*)in +
                                           ((size_t)b * C + cc) * 1024 + l0 + lw);
      v = make_float4(bf2f(u4.x), bf2f(u4.y), bf2f(u4.z), bf2f(u4.w));
    } else {
      v = *(const float4*)(in + ((size_t)b * C + cc) * 1024 + l0 + lw);
    }
    if (RAW) {
      lsr[c][lw + 0] = f2bf(v.x);
      lsr[c][lw + 1] = f2bf(v.y);
      lsr[c][lw + 2] = f2bf(v.z);
      lsr[c][lw + 3] = f2bf(v.w);
    }
    float o[4] = {v.x * sc + bi, v.y * sc + bi, v.z * sc + bi, v.w * sc + bi};
    if (SILU) {
#pragma unroll
      for (int d = 0; d < 4; ++d) o[d] = o[d] / (1.f + __expf(-o[d]));
    }
#pragma unroll
    for (int d = 0; d < 4; ++d) ls[c][lw + d] = o[d];
  }
  __syncthreads();
  const int l = t >> 2, c16 = (t & 3) * 16;
  short8 v0, v1;
#pragma unroll
  for (int j = 0; j < 8; ++j) v0[j] = (short)f2bf(ls[c16 + j][l]);
#pragma unroll
  for (int j = 0; j < 8; ++j) v1[j] = (short)f2bf(ls[c16 + 8 + j][l]);
  unsigned short* ob = outT + ((size_t)b * 1026 + l0 + l + 1) * C + c0 + c16;
  *(short8*)ob = v0;
  *(short8*)(ob + 8) = v1;
  if (RAW) {
    short8 w0, w1;
#pragma unroll
    for (int j = 0; j < 8; ++j) w0[j] = (short)lsr[c16 + j][l];
#pragma unroll
    for (int j = 0; j < 8; ++j) w1[j] = (short)lsr[c16 + 8 + j][l];
    unsigned short* rb = rawT + ((size_t)b * 1026 + l0 + l + 1) * C + c0 + c16;
    *(short8*)rb = w0;
    *(short8*)(rb + 8) = w1;
  }
  if (PADZ) {
    const short8 z = {};
    if (blockIdx.x == 0 && t < 8)
      *(short8*)(outT + (size_t)b * 1026 * C + c0 + t * 8) = z;
    if (blockIdx.x == 15 && t < 8)
      *(short8*)(outT + ((size_t)b * 1026 + 1025) * C + c0 + t * 8) = z;
  }
}

// ---------------- streaming gn1 normalize: Xt1 = silu(norm(H0t)) ------------
__global__ __launch_bounds__(256) void ntE_kernel(
    const unsigned short* __restrict__ Ht, const float2* __restrict__ part,
    const float* __restrict__ gw, const float* __restrict__ gb,
    unsigned short* __restrict__ outT) {
  __shared__ float2 gstat[32];
  const int b = blockIdx.y;
  const int t = threadIdx.x;
  if (t < 32) {
    const float2* p = part + (((size_t)b * 4 + (t >> 3)) * 8 + (t & 7)) * 8;
    float s = 0.f, ss = 0.f;
#pragma unroll
    for (int i = 0; i < 8; ++i) { s += p[i].x; ss += p[i].y; }
    const float mean = s * (1.f / 16384.f);
    const float var = ss * (1.f / 16384.f) - mean * mean;
    gstat[t] = make_float2(mean, rsqrtf(var + 1e-5f));
  }
  __syncthreads();
  const int c8 = t & 63;
  const float2 ms = gstat[c8 >> 1];
  const int cbase = c8 * 8;
  const float4 g0 = *(const float4*)(gw + cbase);
  const float4 g1 = *(const float4*)(gw + cbase + 4);
  const float4 b0 = *(const float4*)(gb + cbase);
  const float4 b1 = *(const float4*)(gb + cbase + 4);
  float sc[8], bi[8];
  sc[0] = g0.x * ms.y; sc[1] = g0.y * ms.y; sc[2] = g0.z * ms.y; sc[3] = g0.w * ms.y;
  sc[4] = g1.x * ms.y; sc[5] = g1.y * ms.y; sc[6] = g1.z * ms.y; sc[7] = g1.w * ms.y;
  bi[0] = b0.x - ms.x * sc[0]; bi[1] = b0.y - ms.x * sc[1];
  bi[2] = b0.z - ms.x * sc[2]; bi[3] = b0.w - ms.x * sc[3];
  bi[4] = b1.x - ms.x * sc[4]; bi[5] = b1.y - ms.x * sc[5];
  bi[6] = b1.z - ms.x * sc[6]; bi[7] = b1.w - ms.x * sc[7];
#pragma unroll
  for (int pass = 0; pass < 4; ++pass) {
    const int lp = blockIdx.x * 16 + pass * 4 + (t >> 6) + 1;
    const size_t o = ((size_t)b * 1026 + lp) * 512 + cbase;
    const short8 v = *(const short8*)(Ht + o);
    short8 r;
#pragma unroll
    for (int e = 0; e < 8; ++e) {
      const float y = bf2f((unsigned short)v[e]) * sc[e] + bi[e];
      r[e] = (short)f2bf(y / (1.f + __expf(-y)));
    }
    *(short8*)(outT + o) = r;
  }
  const short8 z = {};
  if (blockIdx.x == 0 && t < 64)
    *(short8*)(outT + (size_t)b * 1026 * 512 + t * 8) = z;
  if (blockIdx.x == 63 && t < 64)
    *(short8*)(outT + ((size_t)b * 1026 + 1025) * 512 + t * 8) = z;
}

// ---------------- conv as implicit MFMA GEMM ----------------
// K==1: BK=128 (two 64-ci chunks per barrier round, 64KB LDS, 2 blocks/CU).
// K==3: single-buffered BK=64.
template<int K, bool ADD, bool SCATTER, bool FUSE, bool STATS, bool TROUT,
         bool OUT16, bool ADD16>
__global__ __launch_bounds__(256, 2) void convmm_kernel(
    const unsigned short* __restrict__ Xt, const unsigned short* __restrict__ Wt,
    const float* __restrict__ bias, const float* __restrict__ addsrc,
    float* __restrict__ outp,
    unsigned short* __restrict__ qd, unsigned short* __restrict__ kd,
    unsigned short* __restrict__ vd, int Cin, int Cout,
    const unsigned short* __restrict__ X2, const unsigned short* __restrict__ W2,
    const float* __restrict__ bias2, int Cin2, float2* __restrict__ part) {
  constexpr int XR = 160;   // K=3 staged X rows
  constexpr int SMEM_SHORTS = (K == 3) ? (3 * 128 * 64 + XR * 64) : 32768;
  __shared__ __align__(16) unsigned short smem[SMEM_SHORTS];
  const int t = threadIdx.x, lane = t & 63, w = t >> 6;
  const int b = blockIdx.z, co0 = blockIdx.y * 128, l0 = blockIdx.x * 128;
  const int m0 = (w >> 1) * 64, n0 = (w & 1) * 64;
  f32x4 acc[4][4] = {};
  if constexpr (K == 1) {
    // ---- BK=128: stage two 64-ci chunks, one barrier pair per round ----
    for (int ci0 = 0; ci0 < Cin; ci0 += 128) {
      __syncthreads();
#pragma unroll
      for (int half = 0; half < 2; ++half) {
        unsigned short* wB = smem + half * 16384;
        unsigned short* xB = wB + 8192;
        const int cc = ci0 + half * 64;
        for (int rr = 0; rr < 4; ++rr) {
          const int row = rr * 32 + (t >> 3);
          const int c16 = (t & 7) ^ (row & 7);
          gload_lds16(Wt + (size_t)(co0 + row) * Cin + cc + c16 * 8,
                      (char*)wB + (rr * 256 + t) * 16);
        }
        for (int rr = 0; rr < 4; ++rr) {
          const int r = rr * 32 + (t >> 3);
          const int lp = l0 + 1 + r;
          const int c16 = (t & 7) ^ (r & 7);
          gload_lds16(Xt + ((size_t)b * 1026 + lp) * Cin + cc + c16 * 8,
                      (char*)xB + (rr * 256 + t) * 16);
        }
      }
      __syncthreads();
#pragma unroll
      for (int half = 0; half < 2; ++half) {
        const unsigned short* wT = smem + half * 16384;
        const unsigned short* xT = wT + 8192;
#pragma unroll
        for (int ks = 0; ks < 2; ++ks) {
          short8 af[4], bfr[4];
#pragma unroll
          for (int mf = 0; mf < 4; ++mf) {
            const int row = m0 + mf * 16 + (lane & 15);
            const int u = row * 8 + ((ks * 4 + (lane >> 4)) ^ (row & 7));
            af[mf] = *(const short8*)(wT + u * 8);
          }
#pragma unroll
          for (int nf = 0; nf < 4; ++nf) {
            const int r = n0 + nf * 16 + (lane & 15);
            const int u = r * 8 + ((ks * 4 + (lane >> 4)) ^ (r & 7));
            bfr[nf] = *(const short8*)(xT + u * 8);
          }
#pragma unroll
          for (int mf = 0; mf < 4; ++mf)
#pragma unroll
            for (int nf = 0; nf < 4; ++nf)
              acc[mf][nf] = __builtin_amdgcn_mfma_f32_16x16x32_bf16(
                  af[mf], bfr[nf], acc[mf][nf], 0, 0, 0);
        }
      }
    }
  } else {
    unsigned short* wT = smem;
    unsigned short* xT = smem + K * 128 * 64;
    const int START = l0;
    for (int ci0 = 0; ci0 < Cin; ci0 += 64) {
      __syncthreads();
      for (int rr = 0; rr < K * 4; ++rr) {
        const int row = rr * 32 + (t >> 3);
        const int co = row & 127;
        const int c16 = (t & 7) ^ (co & 7);
        gload_lds16(Wt + ((size_t)(row >> 7) * Cout + co0 + co) * Cin + ci0 + c16 * 8,
                    (char*)wT + (rr * 256 + t) * 16);
      }
      for (int rr = 0; rr < XR / 32; ++rr) {
        const int r = rr * 32 + (t >> 3);
        int lp = START + r;
        if (lp > 1025) lp = 1025;
        const int c16 = (t & 7) ^ (r & 7);
        gload_lds16(Xt + ((size_t)b * 1026 + lp) * Cin + ci0 + c16 * 8,
                    (char*)xT + (rr * 256 + t) * 16);
      }
      __syncthreads();
#pragma unroll
      for (int kk = 0; kk < K; ++kk) {
#pragma unroll
        for (int ks = 0; ks < 2; ++ks) {
          short8 af[4], bfr[4];
#pragma unroll
          for (int mf = 0; mf < 4; ++mf) {
            const int row = m0 + mf * 16 + (lane & 15);
            const int u = (kk * 128 + row) * 8 + ((ks * 4 + (lane >> 4)) ^ (row & 7));
            af[mf] = *(const short8*)(wT + u * 8);
          }
#pragma unroll
          for (int nf = 0; nf < 4; ++nf) {
            const int r = n0 + nf * 16 + (lane & 15) + kk;
            const int u = r * 8 + ((ks * 4 + (lane >> 4)) ^ (r & 7));
            bfr[nf] = *(const short8*)(xT + u * 8);
          }
#pragma unroll
          for (int mf = 0; mf < 4; ++mf)
#pragma unroll
            for (int nf = 0; nf < 4; ++nf)
              acc[mf][nf] = __builtin_amdgcn_mfma_f32_16x16x32_bf16(
                  af[mf], bfr[nf], acc[mf][nf], 0, 0, 0);
        }
      }
    }
    if (FUSE) {
      for (int ci0 = 0; ci0 < Cin2; ci0 += 64) {
        __syncthreads();
        for (int rr = 0; rr < 4; ++rr) {
          const int co = rr * 32 + (t >> 3);
          const int c16 = (t & 7) ^ (co & 7);
          gload_lds16(W2 + (size_t)(co0 + co) * Cin2 + ci0 + c16 * 8,
                      (char*)wT + (rr * 256 + t) * 16);
        }
        for (int rr = 0; rr < 4; ++rr) {
          const int r = rr * 32 + (t >> 3);
          const int lp = l0 + 1 + r;
          const int c16 = (t & 7) ^ (r & 7);
          gload_lds16(X2 + ((size_t)b * 1026 + lp) * Cin2 + ci0 + c16 * 8,
                      (char*)xT + (rr * 256 + t) * 16);
        }
        __syncthreads();
#pragma unroll
        for (int ks = 0; ks < 2; ++ks) {
          short8 af[4], bfr[4];
#pragma unroll
          for (int mf = 0; mf < 4; ++mf) {
            const int row = m0 + mf * 16 + (lane & 15);
            const int u = row * 8 + ((ks * 4 + (lane >> 4)) ^ (row & 7));
            af[mf] = *(const short8*)(wT + u * 8);
          }
#pragma unroll
          for (int nf = 0; nf < 4; ++nf) {
            const int r = n0 + nf * 16 + (lane & 15);
            const int u = r * 8 + ((ks * 4 + (lane >> 4)) ^ (r & 7));
            bfr[nf] = *(const short8*)(xT + u * 8);
          }
#pragma unroll
          for (int mf = 0; mf < 4; ++mf)
#pragma unroll
            for (int nf = 0; nf < 4; ++nf)
              acc[mf][nf] = __builtin_amdgcn_mfma_f32_16x16x32_bf16(
                  af[mf], bfr[nf], acc[mf][nf], 0, 0, 0);
        }
      }
    }
  }
  if (TROUT) {
    __syncthreads();
    unsigned short* TP = smem;
    float2* sr = (float2*)(TP + 128 * 128);
    float sg[4] = {}, ssg[4] = {};
#pragma unroll
    for (int mf = 0; mf < 4; ++mf)
#pragma unroll
      for (int r = 0; r < 4; ++r) {
        const int mloc = m0 + mf * 16 + (lane >> 4) * 4 + r;
        const float bv = bias[co0 + mloc];
#pragma unroll
        for (int nf = 0; nf < 4; ++nf) {
          const int l = n0 + nf * 16 + (lane & 15);
          const float v = acc[mf][nf][r] + bv;
          sg[mf] += v; ssg[mf] += v * v;
          const int u = l * 16 + ((mloc >> 3) ^ (l & 7));
          TP[u * 8 + (mloc & 7)] = f2bf(v);
        }
      }
#pragma unroll
    for (int mf = 0; mf < 4; ++mf) {
      float s = sg[mf], ss = ssg[mf];
#pragma unroll
      for (int off = 32; off; off >>= 1) {
        s += __shfl_down(s, off);
        ss += __shfl_down(ss, off);
      }
      if (lane == 0)
        sr[(((w >> 1) * 4 + mf) << 1) | (w & 1)] = make_float2(s, ss);
    }
    __syncthreads();
    for (int it = 0; it < 8; ++it) {
      const int idx = it * 256 + t;
      const int l = idx >> 4, mu = idx & 15;
      const short8 v = *(const short8*)(TP + (l * 16 + (mu ^ (l & 7))) * 8);
      *(short8*)(qd + ((size_t)b * 1026 + l0 + l + 1) * 512 + co0 + mu * 8) = v;
    }
    if (t < 8) {
      const float2 a = sr[t * 2], c = sr[t * 2 + 1];
      part[(((size_t)b * 4 + blockIdx.y) * 8 + t) * 8 + blockIdx.x] =
          make_float2(a.x + c.x, a.y + c.y);
    }
  } else if (!SCATTER) {
    float sg[4] = {}, ssg[4] = {};
#pragma unroll
    for (int mf = 0; mf < 4; ++mf) {
#pragma unroll
      for (int r = 0; r < 4; ++r) {
        const int co = co0 + m0 + mf * 16 + (lane >> 4) * 4 + r;
        float bv = bias[co];
        if (FUSE) bv += bias2[co];
#pragma unroll
        for (int nf = 0; nf < 4; ++nf) {
          const int l = l0 + n0 + nf * 16 + (lane & 15);
          const size_t o = ((size_t)b * Cout + co) * 1024 + l;
          float v = acc[mf][nf][r] + bv;
          if (ADD) {
            if (ADD16) v += bf2f(((const unsigned short*)addsrc)[o]);
            else       v += addsrc[o];
          }
          if (OUT16) ((unsigned short*)outp)[o] = f2bf(v);
          else       outp[o] = v;
          if (STATS) { sg[mf] += v; ssg[mf] += v * v; }
        }
      }
    }
    if (STATS) {
      __syncthreads();
      float2* sr = (float2*)smem;
#pragma unroll
      for (int mf = 0; mf < 4; ++mf) {
        float s = sg[mf], ss = ssg[mf];
#pragma unroll
        for (int off = 32; off; off >>= 1) {
          s += __shfl_down(s, off);
          ss += __shfl_down(ss, off);
        }
        if (lane == 0)
          sr[(((w >> 1) * 4 + mf) << 1) | (w & 1)] = make_float2(s, ss);
      }
      __syncthreads();
      if (t < 8) {
        const float2 a = sr[t * 2], c = sr[t * 2 + 1];
        part[(((size_t)b * 4 + blockIdx.y) * 8 + t) * 8 + blockIdx.x] =
            make_float2(a.x + c.x, a.y + c.y);
      }
    }
  } else {
    __syncthreads();
    unsigned short* TP = smem;
    const int sidx = co0 >> 9;            // 0=Q 1=K 2=V
    const int mbase = co0 & 511;
    const float qscale = (sidx == 0) ? 0.18033688f : 1.0f;  // 0.125*log2e
    if (sidx < 2) {
#pragma unroll
      for (int mf = 0; mf < 4; ++mf)
#pragma unroll
        for (int r = 0; r < 4; ++r) {
          const int mloc = m0 + mf * 16 + (lane >> 4) * 4 + r;
          const int mg = mbase + mloc;
          const float bv = bias[(mg >> 6) * 192 + (mg & 63) * 3 + sidx];
#pragma unroll
          for (int nf = 0; nf < 4; ++nf) {
            const int l = n0 + nf * 16 + (lane & 15);
            const int u = l * 16 + ((mloc >> 3) ^ (l & 7));
            TP[u * 8 + (mloc & 7)] = f2bf((acc[mf][nf][r] + bv) * qscale);
          }
        }
      __syncthreads();
      unsigned short* dst = (sidx == 0) ? qd : kd;
      for (int it = 0; it < 8; ++it) {
        const int idx = it * 256 + t;
        const int l = idx >> 4, mu = idx & 15;
        const int mg = mbase + mu * 8;
        const int bh = b * 8 + (mg >> 6);
        const short8 v = *(const short8*)(TP + (l * 16 + (mu ^ (l & 7))) * 8);
        *(short8*)(dst + ((size_t)bh * 1024 + l0 + l) * 64 + (mg & 63)) = v;
      }
    } else {
#pragma unroll
      for (int mf = 0; mf < 4; ++mf)
#pragma unroll
        for (int r = 0; r < 4; ++r) {
          const int mloc = m0 + mf * 16 + (lane >> 4) * 4 + r;
          const int mg = mbase + mloc;
          const float bv = bias[(mg >> 6) * 192 + (mg & 63) * 3 + 2];
#pragma unroll
          for (int nf = 0; nf < 4; ++nf) {
            const int l = n0 + nf * 16 + (lane & 15);
            const int u = mloc * 16 + ((l >> 3) ^ ((mloc & 7) << 1));
            TP[u * 8 + (l & 7)] = f2bf(acc[mf][nf][r] + bv);
          }
        }
      __syncthreads();
      for (int it = 0; it < 8; ++it) {
        const int idx = it * 256 + t;
        const int mloc = idx >> 4, lu = idx & 15;
        const int mg = mbase + mloc;
        const int bh = b * 8 + (mg >> 6);
        const short8 v =
            *(const short8*)(TP + (mloc * 16 + (lu ^ ((mloc & 7) << 1))) * 8);
        *(short8*)(vd + ((size_t)bh * 64 + (mg & 63)) * 1024 + l0 + lu * 8) = v;
      }
    }
  }
}

// ---------------- flash attention, swapped-QK^T 32x32 MFMA ----------------
// QBLK=256: 4 waves x 64 q-rows (2 i-frags each); K/V frags read once per kc
// and shared across both i-frags. 32 KB LDS, 2 blocks/CU, no online max.
__global__ __launch_bounds__(256, 2) void attn_mfma(
    const unsigned short* __restrict__ Qb, const unsigned short* __restrict__ Kb,
    const unsigned short* __restrict__ Vb, unsigned short* __restrict__ Ab) {
  __shared__ __align__(16) unsigned short Ks[2][64 * 64]; // [j][c] swz, 16 KB
  __shared__ __align__(16) unsigned short Vs[2][64 * 64]; // [c][j] swz, 16 KB
  unsigned short* QP = &Ks[0][0];   // 32 KB overlay: Q staging (256x64), O^T
  const int t = threadIdx.x, lane = t & 63, w = t >> 6;
  const int hi = lane >> 5, l31 = lane & 31;
  const int id = blockIdx.x;
  const int xcd = id & 7, local = id >> 3;     // 16 bh per XCD, 4 q-tiles each
  const int bh = (xcd << 4) | (local >> 2);
  const int b = bh >> 3, h = bh & 7;
  const int iq0 = (local & 3) * 256;
  const unsigned short* Qg = Qb + ((size_t)bh * 1024 + iq0) * 64;
  const unsigned short* Kg = Kb + (size_t)bh * 1024 * 64;
  const unsigned short* Vg = Vb + (size_t)bh * 64 * 1024;
  // ---- prologue: stage 256-row Q through the whole 32KB region ----
  for (int rr = 0; rr < 8; ++rr) {
    const int r = rr * 32 + (t >> 3), c16 = (t & 7) ^ (r & 7);
    gload_lds16(Qg + (size_t)r * 64 + c16 * 8, (char*)QP + (rr * 256 + t) * 16);
  }
  __syncthreads();
  const int irow0 = w * 64 + l31;
  const int irow1 = w * 64 + 32 + l31;
  short8 qf[2][4];
#pragma unroll
  for (int kc = 0; kc < 4; ++kc) {
    const int u0 = irow0 * 8 + ((kc * 2 + hi) ^ (irow0 & 7));
    const int u1 = irow1 * 8 + ((kc * 2 + hi) ^ (irow1 & 7));
    qf[0][kc] = *(const short8*)(QP + u0 * 8);
    qf[1][kc] = *(const short8*)(QP + u1 * 8);
  }
  __syncthreads();   // all Q reads done before K/V staging overwrites
  for (int rr = 0; rr < 2; ++rr) {
    const int r = rr * 32 + (t >> 3), c16 = (t & 7) ^ (r & 7);
    gload_lds16(Kg + (size_t)r * 64 + c16 * 8, (char*)Ks[0] + (rr * 256 + t) * 16);
    gload_lds16(Vg + (size_t)r * 1024 + c16 * 8, (char*)Vs[0] + (rr * 256 + t) * 16);
  }
  __syncthreads();
  float ls0 = 0.f, ls1 = 0.f;
  f32x16 oA[2][2] = {};   // [ifrag][cfrag]
  auto kv_iter = [&](const int ti, const int cur) {
    if (ti < 15) {
      const int j1 = (ti + 1) * 64;
      for (int rr = 0; rr < 2; ++rr) {
        const int r = rr * 32 + (t >> 3), c16 = (t & 7) ^ (r & 7);
        gload_lds16(Kg + (size_t)(j1 + r) * 64 + c16 * 8,
                    (char*)Ks[cur ^ 1] + (rr * 256 + t) * 16);
        gload_lds16(Vg + (size_t)r * 1024 + j1 + c16 * 8,
                    (char*)Vs[cur ^ 1] + (rr * 256 + t) * 16);
      }
    }
    // ---- S^T for both i-frags; K frags read once per kc ----
    f32x16 s00 = {}, s01 = {}, s10 = {}, s11 = {};   // [ifrag][jfrag]
    __builtin_amdgcn_s_setprio(1);
#pragma unroll
    for (int kc = 0; kc < 4; ++kc) {
      const int r0 = l31, r1 = 32 + l31;
      const short8 k0 = *(const short8*)(Ks[cur] + (r0 * 8 + ((kc * 2 + hi) ^ (r0 & 7))) * 8);
      const short8 k1 = *(const short8*)(Ks[cur] + (r1 * 8 + ((kc * 2 + hi) ^ (r1 & 7))) * 8);
      s00 = __builtin_amdgcn_mfma_f32_32x32x16_bf16(k0, qf[0][kc], s00, 0, 0, 0);
      s01 = __builtin_amdgcn_mfma_f32_32x32x16_bf16(k1, qf[0][kc], s01, 0, 0, 0);
      s10 = __builtin_amdgcn_mfma_f32_32x32x16_bf16(k0, qf[1][kc], s10, 0, 0, 0);
      s11 = __builtin_amdgcn_mfma_f32_32x32x16_bf16(k1, qf[1][kc], s11, 0, 0, 0);
    }
    __builtin_amdgcn_s_setprio(0);
    // ---- p = exp2(S); lane-local partial sums ----
    short8 pb0[4], pb1[4];
    {
      float p0 = 0.f, p1 = 0.f, p2 = 0.f, p3 = 0.f;
#pragma unroll
      for (int r = 0; r < 16; ++r) { s00[r] = fexp2(s00[r]); }
#pragma unroll
      for (int r = 0; r < 16; r += 4) {
        p0 += s00[r + 0]; p1 += s00[r + 1]; p2 += s00[r + 2]; p3 += s00[r + 3];
      }
#pragma unroll
      for (int r = 0; r < 16; ++r) { s01[r] = fexp2(s01[r]); }
#pragma unroll
      for (int r = 0; r < 16; r += 4) {
        p0 += s01[r + 0]; p1 += s01[r + 1]; p2 += s01[r + 2]; p3 += s01[r + 3];
      }
      ls0 += (p0 + p1) + (p2 + p3);
      pb0[0] = PACK8(s00, 0); pb0[1] = PACK8(s00, 8);
      pb0[2] = PACK8(s01, 0); pb0[3] = PACK8(s01, 8);
    }
    {
      float p0 = 0.f, p1 = 0.f, p2 = 0.f, p3 = 0.f;
#pragma unroll
      for (int r = 0; r < 16; ++r) { s10[r] = fexp2(s10[r]); }
#pragma unroll
      for (int r = 0; r < 16; r += 4) {
        p0 += s10[r + 0]; p1 += s10[r + 1]; p2 += s10[r + 2]; p3 += s10[r + 3];
      }
#pragma unroll
      for (int r = 0; r < 16; ++r) { s11[r] = fexp2(s11[r]); }
#pragma unroll
      for (int r = 0; r < 16; r += 4) {
        p0 += s11[r + 0]; p1 += s11[r + 1]; p2 += s11[r + 2]; p3 += s11[r + 3];
      }
      ls1 += (p0 + p1) + (p2 + p3);
      pb1[0] = PACK8(s10, 0); pb1[1] = PACK8(s10, 8);
      pb1[2] = PACK8(s11, 0); pb1[3] = PACK8(s11, 8);
    }
    // ---- PV: V frags read once per (cf,s), feed both i-frags ----
    __builtin_amdgcn_s_setprio(1);
#pragma unroll
    for (int cf = 0; cf < 2; ++cf) {
      const int row = cf * 32 + l31;
#pragma unroll
      for (int s = 0; s < 4; ++s) {
        const int u = row * 8 + ((s * 2 + hi) ^ (row & 7));
        const short8 va = *(const short8*)(Vs[cur] + u * 8);
        oA[0][cf] = __builtin_amdgcn_mfma_f32_32x32x16_bf16(va, pb0[s], oA[0][cf], 0, 0, 0);
        oA[1][cf] = __builtin_amdgcn_mfma_f32_32x32x16_bf16(va, pb1[s], oA[1][cf], 0, 0, 0);
      }
    }
    __builtin_amdgcn_s_setprio(0);
    __syncthreads();   // staging drained + all reads of cur done
  };
  for (int ti = 0; ti < 16; ti += 2) {
    kv_iter(ti, 0);
    kv_iter(ti + 1, 1);
  }
  // ---- finalize: per-ifrag 1/l; O^T via 32KB overlay (wave-private rows) ----
  const float inv0 = 1.f / swap_add(ls0);
  const float inv1 = 1.f / swap_add(ls1);
#pragma unroll
  for (int f = 0; f < 2; ++f) {
    const int irow = f ? irow1 : irow0;
    const float inv = f ? inv1 : inv0;
#pragma unroll
    for (int cf = 0; cf < 2; ++cf)
#pragma unroll
      for (int r = 0; r < 16; ++r) {
        const int c = cf * 32 + (r & 3) + 8 * (r >> 2) + 4 * hi;
        const int u = irow * 8 + ((c >> 3) ^ (irow & 7));
        QP[u * 8 + (c & 7)] = f2bf(oA[f][cf][r] * inv);
      }
  }
  for (int rr = 0; rr < 8; ++rr) {
    const int row = w * 64 + rr * 8 + (lane >> 3);
    const int c16 = lane & 7;
    const int u = row * 8 + (c16 ^ (row & 7));
    const short8 vv = *(const short8*)(QP + u * 8);
    *(short8*)(Ab + ((size_t)b * 1026 + iq0 + row + 1) * 512 + h * 64 + c16 * 8) = vv;
  }
}

// ---------------------------------------------------------------------------
#define MB(x) ((size_t)(x) << 20)

extern "C" void kernel_launch(void* const* d_in, const int* in_sizes, int n_in,
                              void* d_out, int out_size, void* d_ws,
                              size_t ws_size, hipStream_t stream) {
  const float* x   = (const float*)d_in[0];
  const float* n0w = (const float*)d_in[1];
  const float* n0b = (const float*)d_in[2];
  const float* c0w = (const float*)d_in[3];
  const float* c0b = (const float*)d_in[4];
  const float* n1w = (const float*)d_in[5];
  const float* n1b = (const float*)d_in[6];
  const float* c1w = (const float*)d_in[7];
  const float* c1b = (const float*)d_in[8];
  const float* skw = (const float*)d_in[9];
  const float* skb = (const float*)d_in[10];
  const float* n2w = (const float*)d_in[11];
  const float* n2b = (const float*)d_in[12];
  const float* qw  = (const float*)d_in[13];
  const float* qb  = (const float*)d_in[14];
  const float* pw  = (const float*)d_in[15];
  const float* pb  = (const float*)d_in[16];
  char* wsb = (char*)d_ws;
  unsigned short* WT0 = (unsigned short*)(wsb);            // 0.79 MB
  unsigned short* WT1 = (unsigned short*)(wsb + MB(1));    // 1.5 MB
  unsigned short* WSK = (unsigned short*)(wsb + MB(3));    // 0.26 MB
  unsigned short* WQ  = (unsigned short*)(wsb + MB(4));    // 1.5 MB
  unsigned short* WP  = (unsigned short*)(wsb + MB(6));    // 0.5 MB
  unsigned short* H2b = (unsigned short*)(wsb + MB(7));    // 16.8 MB bf16, to end
  unsigned short* Qb2 = (unsigned short*)(wsb + MB(41));   // 16 MB
  unsigned short* Kb2 = (unsigned short*)(wsb + MB(58));   // 16 MB
  unsigned short* H0t = (unsigned short*)(wsb + MB(75));   // 16 MB, dead after ntE
  unsigned short* Vb2 = (unsigned short*)(wsb + MB(75));   // 16.8 MB (reuses H0t)
  unsigned short* Xt2 = (unsigned short*)(wsb + MB(92));   // 16 MB
  unsigned short* Xt0 = (unsigned short*)(wsb + MB(109));  // 8.4 MB, dead after conv0
  unsigned short* Xt1 = (unsigned short*)(wsb + MB(109));  // 16.8 MB, dead after conv1
  unsigned short* Ab  = (unsigned short*)(wsb + MB(109));  // 16.8 MB (reuses Xt1)
  unsigned short* Xbf = (unsigned short*)(wsb + MB(126));  // 8.4 MB
  float2* MR0   = (float2*)(wsb + MB(135));                // 4 KB
  float2* PART1 = (float2*)(wsb + MB(135) + 8192);         // 16 KB
  float2* PART2 = (float2*)(wsb + MB(135) + 32768);        // 16 KB
  float* outp = (float*)d_out;

  // weight conversions + gn0 stats in one launch
  prep_stats<<<9728, 256, 0, stream>>>(c0w, c1w, skw, qw, pw,
                                       WT0, WT1, WSK, WQ, WP, x, MR0, Xt0);
  // Xt0 = silu(gn0(x)) transposed; Xbf = raw x transposed (dual output)
  nt_kernel<1, true, 256, false, true, false><<<dim3(16, 4, 16), 256, 0, stream>>>(
      x, MR0, n0w, n0b, Xt0, Xbf);
  // H0t = conv0(Xt0)  (bf16 transposed out + gn1 stats partials)
  convmm_kernel<3, false, false, false, true, true, false, false>
      <<<dim3(8, 4, 16), 256, 0, stream>>>(
      Xt0, WT0, c0b, nullptr, nullptr, H0t, nullptr, nullptr, 256, 512,
      nullptr, nullptr, nullptr, 0, PART1);
  // Xt1 = silu(gn1(H0t))  (streaming)
  ntE_kernel<<<dim3(64, 16), 256, 0, stream>>>(H0t, PART1, n1w, n1b, Xt1);
  // H2 (bf16) = conv1(Xt1) + skip(Xbf)  (fused; + gn2 stats partials)
  convmm_kernel<3, false, false, true, true, false, true, false>
      <<<dim3(8, 4, 16), 256, 0, stream>>>(
      Xt1, WT1, c1b, nullptr, (float*)H2b, nullptr, nullptr, nullptr, 512, 512,
      Xbf, WSK, skb, 256, PART2);
  // Xt2 = gn2(H2)  (bf16 input)
  nt_kernel<2, false, 512, false, false, true><<<dim3(16, 8, 16), 256, 0, stream>>>(
      (const float*)H2b, PART2, n2w, n2b, Xt2, nullptr);
  // qkv (layout-native scatter; Q pre-scaled; BK=128)
  convmm_kernel<1, false, true, false, false, false, false, false>
      <<<dim3(8, 12, 16), 256, 0, stream>>>(
      Xt2, WQ, qb, nullptr, nullptr, Qb2, Kb2, Vb2, 512, 1536,
      nullptr, nullptr, nullptr, 0, nullptr);
  // a = attention(q,k,v)
  attn_mfma<<<dim3(512), 256, 0, stream>>>(Qb2, Kb2, Vb2, Ab);
  // out = h + proj(a)  (bf16 residual read; BK=128)
  convmm_kernel<1, true, false, false, false, false, false, true>
      <<<dim3(8, 4, 16), 256, 0, stream>>>(
      Ab, WP, pb, (const float*)H2b, outp, nullptr, nullptr, nullptr, 512, 512,
      nullptr, nullptr, nullptr, 0, nullptr);
}

// Round 17
// 175.939 us; speedup vs baseline: 1.0093x; 1.0093x over previous
//
#include <hip/hip_runtime.h>

// ---------------------------------------------------------------------------
// UNetBlock1D — bf16 MFMA, round 17 (= round-12/15 config, best measured
// 176.3us, triple-confirmed). BK=128 (r16) reverted: null/negative.
// B=16, CIN=256, COUT=512, L=1024, K=3, HEADS=8 (ch=64), GROUPS=32.
//
// Validated structure:
//  * all convs = implicit MFMA GEMM, 128co x 128l tiles, BK=64, 2 blocks/CU
//  * conv0 -> bf16 transposed out + fused gn1 stats; conv1 fuses skip as a
//    second GEMM-K pass + gn2 stats; qkv layout-native (s-major weights +
//    LDS-transpose epilogue); proj reads bf16 residual
//  * attention: swapped-QK^T 32x32 MFMA, QBLK=256 (2 i-frags/wave), no
//    online max (exp2 shift-invariance), in-register P via cvt_pk+permlane,
//    XCD-pinned K/V, 32KB LDS, raw v_exp_f32
// ---------------------------------------------------------------------------

typedef float f32x4 __attribute__((ext_vector_type(4)));
typedef float f32x16 __attribute__((ext_vector_type(16)));
typedef short short8 __attribute__((ext_vector_type(8)));

__device__ __forceinline__ unsigned short f2bf(float f) {
  union { float f; unsigned u; } v; v.f = f;
  return (unsigned short)((v.u + 0x7FFFu + ((v.u >> 16) & 1u)) >> 16);
}
__device__ __forceinline__ float bf2f(unsigned short h) {
  union { unsigned u; float f; } v; v.u = ((unsigned)h) << 16;
  return v.f;
}

__device__ __forceinline__ float fexp2(float x) {
  float r;
  asm("v_exp_f32 %0, %1" : "=v"(r) : "v"(x));
  return r;
}

__device__ __forceinline__ void gload_lds16(const void* g, void* l) {
  __builtin_amdgcn_global_load_lds(
      (const __attribute__((address_space(1))) unsigned int*)g,
      (__attribute__((address_space(3))) unsigned int*)l, 16, 0, 0);
}

// cross-half (lane ^ 32) combine via v_permlane32_swap_b32 (VALU)
__device__ __forceinline__ float swap_add(float x) {
  float a = x, b = x;
  asm("v_permlane32_swap_b32 %0, %1" : "+v"(a), "+v"(b));
  return a + b;
}

// pack 8 per-lane P values into the PV B-fragment short8 via cvt_pk + swap
__device__ __forceinline__ short8 pack8(float a0, float a1, float a2, float a3,
                                        float a4, float a5, float a6, float a7) {
  unsigned x0, x1, x2, x3;
  asm("v_cvt_pk_bf16_f32 %0, %1, %2" : "=v"(x0) : "v"(a0), "v"(a1));
  asm("v_cvt_pk_bf16_f32 %0, %1, %2" : "=v"(x1) : "v"(a2), "v"(a3));
  asm("v_cvt_pk_bf16_f32 %0, %1, %2" : "=v"(x2) : "v"(a4), "v"(a5));
  asm("v_cvt_pk_bf16_f32 %0, %1, %2" : "=v"(x3) : "v"(a6), "v"(a7));
  asm("v_permlane32_swap_b32 %0, %1" : "+v"(x0), "+v"(x2));
  asm("v_permlane32_swap_b32 %0, %1" : "+v"(x1), "+v"(x3));
  union { unsigned u[4]; short8 s; } r;
  r.u[0] = x0; r.u[1] = x1; r.u[2] = x2; r.u[3] = x3;
  return r.s;
}
#define PACK8(V, B) pack8(V[B+0], V[B+1], V[B+2], V[B+3], V[B+4], V[B+5], V[B+6], V[B+7])

// ---------------- merged weight prep + gn0 stats ----------------
// blocks [0,9216): weight conversion; [9216,9728): gn0 stats (CPG=8) + pads.
__global__ __launch_bounds__(256) void prep_stats(
    const float* __restrict__ c0w, const float* __restrict__ c1w,
    const float* __restrict__ skw, const float* __restrict__ qw,
    const float* __restrict__ pw,
    unsigned short* __restrict__ WT0, unsigned short* __restrict__ WT1,
    unsigned short* __restrict__ WSK, unsigned short* __restrict__ WQ,
    unsigned short* __restrict__ WP,
    const float* __restrict__ x, float2* __restrict__ mr,
    unsigned short* __restrict__ outT) {
  __shared__ float2 red[4];
  const int t = threadIdx.x;
  if (blockIdx.x >= 9216) {
    const int blk = blockIdx.x - 9216;
    const int g = blk & 31;
    const int bb = blk >> 5;
    const size_t base = ((size_t)bb * 256 + g * 8) * 1024;
    float s = 0.f, ss = 0.f;
#pragma unroll
    for (int i = t * 4; i < 8192; i += 1024) {
      const float4 v = *(const float4*)(x + base + i);
      s += (v.x + v.y) + (v.z + v.w);
      ss += (v.x * v.x + v.y * v.y) + (v.z * v.z + v.w * v.w);
    }
#pragma unroll
    for (int off = 32; off; off >>= 1) {
      s += __shfl_down(s, off);
      ss += __shfl_down(ss, off);
    }
    if ((t & 63) == 0) red[t >> 6] = make_float2(s, ss);
    __syncthreads();
    const float2 r0 = red[0], r1 = red[1], r2 = red[2], r3 = red[3];
    const float tots = (r0.x + r1.x) + (r2.x + r3.x);
    const float totss = (r0.y + r1.y) + (r2.y + r3.y);
    const float mean = tots * (1.f / 8192.f);
    const float var = totss * (1.f / 8192.f) - mean * mean;
    if (t == 0) mr[bb * 32 + g] = make_float2(mean, rsqrtf(var + 1e-5f));
    unsigned short* ob = outT + (size_t)bb * 1026 * 256 + g * 8;
    if (t < 8) {
      ob[t] = 0;
      ob[(size_t)1025 * 256 + t] = 0;
    }
    return;
  }
  int idx = blockIdx.x * 256 + t;
  if (idx < 393216) {        // WT0[kk][co][ci] <- c0w (512,256,3)
    const int ci = idx & 255; const int rem = idx >> 8;
    const int co = rem & 511; const int kk = rem >> 9;
    WT0[idx] = f2bf(c0w[((size_t)co * 256 + ci) * 3 + kk]); return;
  }
  idx -= 393216;
  if (idx < 786432) {        // WT1[kk][co][ci] <- c1w (512,512,3)
    const int ci = idx & 511; const int rem = idx >> 9;
    const int co = rem & 511; const int kk = rem >> 9;
    WT1[idx] = f2bf(c1w[((size_t)co * 512 + ci) * 3 + kk]); return;
  }
  idx -= 786432;
  if (idx < 131072) { WSK[idx] = f2bf(skw[idx]); return; }
  idx -= 131072;
  if (idx < 786432) {        // WQ s-major permuted
    const int ci = idx & 511; const int m = idx >> 9;
    const int s = m >> 9, rem = m & 511, h = rem >> 6, c = rem & 63;
    WQ[idx] = f2bf(qw[((size_t)(h * 192 + c * 3 + s) * 512) + ci]); return;
  }
  idx -= 786432;
  WP[idx] = f2bf(pw[idx]);
}

// ---------------- norm (+SiLU) + transpose, LDS-tiled, coalesced ------------
template<int MODE, bool SILU, int C, bool PADZ, bool RAW, bool IN16>
__global__ __launch_bounds__(256) void nt_kernel(
    const float* __restrict__ in, const float2* __restrict__ st,
    const float* __restrict__ gw, const float* __restrict__ gb,
    unsigned short* __restrict__ outT, unsigned short* __restrict__ rawT) {
  constexpr int CPG = C / 32;
  __shared__ float ls[64][65];
  __shared__ unsigned short lsr[RAW ? 64 : 1][72];
  __shared__ float2 gstat[4];
  const int b = blockIdx.z, c0 = blockIdx.y * 64, l0 = blockIdx.x * 64;
  const int t = threadIdx.x;
  if (MODE == 2) {
    if (t < 4) {
      const int g = (c0 >> 4) + t;
      const float2* p = st + (((size_t)b * 4 + (g >> 3)) * 8 + (g & 7)) * 8;
      float s = 0.f, ss = 0.f;
#pragma unroll
      for (int i = 0; i < 8; ++i) { s += p[i].x; ss += p[i].y; }
      const float mean = s * (1.f / 16384.f);
      const float var = ss * (1.f / 16384.f) - mean * mean;
      gstat[t] = make_float2(mean, rsqrtf(var + 1e-5f));
    }
    __syncthreads();
  }
  const int lw = (t & 15) * 4;
  const int cr = t >> 4;
#pragma unroll
  for (int p = 0; p < 4; ++p) {
    const int c = p * 16 + cr;
    const int cc = c0 + c;
    float sc = 1.f, bi = 0.f;
    if (MODE == 1) {
      const float2 ms = st[b * 32 + cc / CPG];
      sc = gw[cc] * ms.y;
      bi = gb[cc] - ms.x * sc;
    } else if (MODE == 2) {
      const float2 ms = gstat[c >> 4];
      sc = gw[cc] * ms.y;
      bi = gb[cc] - ms.x * sc;
    }
    float4 v;
    if (IN16) {
      const ushort4 u4 = *(const ushort4*)((const unsigned short*)in +
                                           ((size_t)b * C + cc) * 1024 + l0 + lw);
      v = make_float4(bf2f(u4.x), bf2f(u4.y), bf2f(u4.z), bf2f(u4.w));
    } else {
      v = *(const float4*)(in + ((size_t)b * C + cc) * 1024 + l0 + lw);
    }
    if (RAW) {
      lsr[c][lw + 0] = f2bf(v.x);
      lsr[c][lw + 1] = f2bf(v.y);
      lsr[c][lw + 2] = f2bf(v.z);
      lsr[c][lw + 3] = f2bf(v.w);
    }
    float o[4] = {v.x * sc + bi, v.y * sc + bi, v.z * sc + bi, v.w * sc + bi};
    if (SILU) {
#pragma unroll
      for (int d = 0; d < 4; ++d) o[d] = o[d] / (1.f + __expf(-o[d]));
    }
#pragma unroll
    for (int d = 0; d < 4; ++d) ls[c][lw + d] = o[d];
  }
  __syncthreads();
  const int l = t >> 2, c16 = (t & 3) * 16;
  short8 v0, v1;
#pragma unroll
  for (int j = 0; j < 8; ++j) v0[j] = (short)f2bf(ls[c16 + j][l]);
#pragma unroll
  for (int j = 0; j < 8; ++j) v1[j] = (short)f2bf(ls[c16 + 8 + j][l]);
  unsigned short* ob = outT + ((size_t)b * 1026 + l0 + l + 1) * C + c0 + c16;
  *(short8*)ob = v0;
  *(short8*)(ob + 8) = v1;
  if (RAW) {
    short8 w0, w1;
#pragma unroll
    for (int j = 0; j < 8; ++j) w0[j] = (short)lsr[c16 + j][l];
#pragma unroll
    for (int j = 0; j < 8; ++j) w1[j] = (short)lsr[c16 + 8 + j][l];
    unsigned short* rb = rawT + ((size_t)b * 1026 + l0 + l + 1) * C + c0 + c16;
    *(short8*)rb = w0;
    *(short8*)(rb + 8) = w1;
  }
  if (PADZ) {
    const short8 z = {};
    if (blockIdx.x == 0 && t < 8)
      *(short8*)(outT + (size_t)b * 1026 * C + c0 + t * 8) = z;
    if (blockIdx.x == 15 && t < 8)
      *(short8*)(outT + ((size_t)b * 1026 + 1025) * C + c0 + t * 8) = z;
  }
}

// ---------------- streaming gn1 normalize: Xt1 = silu(norm(H0t)) ------------
__global__ __launch_bounds__(256) void ntE_kernel(
    const unsigned short* __restrict__ Ht, const float2* __restrict__ part,
    const float* __restrict__ gw, const float* __restrict__ gb,
    unsigned short* __restrict__ outT) {
  __shared__ float2 gstat[32];
  const int b = blockIdx.y;
  const int t = threadIdx.x;
  if (t < 32) {
    const float2* p = part + (((size_t)b * 4 + (t >> 3)) * 8 + (t & 7)) * 8;
    float s = 0.f, ss = 0.f;
#pragma unroll
    for (int i = 0; i < 8; ++i) { s += p[i].x; ss += p[i].y; }
    const float mean = s * (1.f / 16384.f);
    const float var = ss * (1.f / 16384.f) - mean * mean;
    gstat[t] = make_float2(mean, rsqrtf(var + 1e-5f));
  }
  __syncthreads();
  const int c8 = t & 63;
  const float2 ms = gstat[c8 >> 1];
  const int cbase = c8 * 8;
  const float4 g0 = *(const float4*)(gw + cbase);
  const float4 g1 = *(const float4*)(gw + cbase + 4);
  const float4 b0 = *(const float4*)(gb + cbase);
  const float4 b1 = *(const float4*)(gb + cbase + 4);
  float sc[8], bi[8];
  sc[0] = g0.x * ms.y; sc[1] = g0.y * ms.y; sc[2] = g0.z * ms.y; sc[3] = g0.w * ms.y;
  sc[4] = g1.x * ms.y; sc[5] = g1.y * ms.y; sc[6] = g1.z * ms.y; sc[7] = g1.w * ms.y;
  bi[0] = b0.x - ms.x * sc[0]; bi[1] = b0.y - ms.x * sc[1];
  bi[2] = b0.z - ms.x * sc[2]; bi[3] = b0.w - ms.x * sc[3];
  bi[4] = b1.x - ms.x * sc[4]; bi[5] = b1.y - ms.x * sc[5];
  bi[6] = b1.z - ms.x * sc[6]; bi[7] = b1.w - ms.x * sc[7];
#pragma unroll
  for (int pass = 0; pass < 4; ++pass) {
    const int lp = blockIdx.x * 16 + pass * 4 + (t >> 6) + 1;
    const size_t o = ((size_t)b * 1026 + lp) * 512 + cbase;
    const short8 v = *(const short8*)(Ht + o);
    short8 r;
#pragma unroll
    for (int e = 0; e < 8; ++e) {
      const float y = bf2f((unsigned short)v[e]) * sc[e] + bi[e];
      r[e] = (short)f2bf(y / (1.f + __expf(-y)));
    }
    *(short8*)(outT + o) = r;
  }
  const short8 z = {};
  if (blockIdx.x == 0 && t < 64)
    *(short8*)(outT + (size_t)b * 1026 * 512 + t * 8) = z;
  if (blockIdx.x == 63 && t < 64)
    *(short8*)(outT + ((size_t)b * 1026 + 1025) * 512 + t * 8) = z;
}

// ---------------- conv as implicit MFMA GEMM (single-buffered, BK=64) -------
template<int K, bool ADD, bool SCATTER, bool FUSE, bool STATS, bool TROUT,
         bool OUT16, bool ADD16>
__global__ __launch_bounds__(256, 2) void convmm_kernel(
    const unsigned short* __restrict__ Xt, const unsigned short* __restrict__ Wt,
    const float* __restrict__ bias, const float* __restrict__ addsrc,
    float* __restrict__ outp,
    unsigned short* __restrict__ qd, unsigned short* __restrict__ kd,
    unsigned short* __restrict__ vd, int Cin, int Cout,
    const unsigned short* __restrict__ X2, const unsigned short* __restrict__ W2,
    const float* __restrict__ bias2, int Cin2, float2* __restrict__ part) {
  constexpr int XR = (K == 3) ? 160 : 128;
  __shared__ __align__(16) unsigned short smem[K * 128 * 64 + XR * 64];
  unsigned short* wT = smem;
  unsigned short* xT = smem + K * 128 * 64;
  const int t = threadIdx.x, lane = t & 63, w = t >> 6;
  const int b = blockIdx.z, co0 = blockIdx.y * 128, l0 = blockIdx.x * 128;
  const int m0 = (w >> 1) * 64, n0 = (w & 1) * 64;
  const int START = (K == 3) ? l0 : (l0 + 1);
  f32x4 acc[4][4] = {};
  for (int ci0 = 0; ci0 < Cin; ci0 += 64) {
    __syncthreads();
    for (int rr = 0; rr < K * 4; ++rr) {
      const int row = rr * 32 + (t >> 3);
      const int co = row & 127;
      const int c16 = (t & 7) ^ (co & 7);
      gload_lds16(Wt + ((size_t)(row >> 7) * Cout + co0 + co) * Cin + ci0 + c16 * 8,
                  (char*)wT + (rr * 256 + t) * 16);
    }
    for (int rr = 0; rr < XR / 32; ++rr) {
      const int r = rr * 32 + (t >> 3);
      int lp = START + r;
      if (lp > 1025) lp = 1025;
      const int c16 = (t & 7) ^ (r & 7);
      gload_lds16(Xt + ((size_t)b * 1026 + lp) * Cin + ci0 + c16 * 8,
                  (char*)xT + (rr * 256 + t) * 16);
    }
    __syncthreads();
#pragma unroll
    for (int kk = 0; kk < K; ++kk) {
#pragma unroll
      for (int ks = 0; ks < 2; ++ks) {
        short8 af[4], bfr[4];
#pragma unroll
        for (int mf = 0; mf < 4; ++mf) {
          const int row = m0 + mf * 16 + (lane & 15);
          const int u = (kk * 128 + row) * 8 + ((ks * 4 + (lane >> 4)) ^ (row & 7));
          af[mf] = *(const short8*)(wT + u * 8);
        }
#pragma unroll
        for (int nf = 0; nf < 4; ++nf) {
          const int r = n0 + nf * 16 + (lane & 15) + kk;
          const int u = r * 8 + ((ks * 4 + (lane >> 4)) ^ (r & 7));
          bfr[nf] = *(const short8*)(xT + u * 8);
        }
#pragma unroll
        for (int mf = 0; mf < 4; ++mf)
#pragma unroll
          for (int nf = 0; nf < 4; ++nf)
            acc[mf][nf] = __builtin_amdgcn_mfma_f32_16x16x32_bf16(
                af[mf], bfr[nf], acc[mf][nf], 0, 0, 0);
      }
    }
  }
  if (FUSE) {
    for (int ci0 = 0; ci0 < Cin2; ci0 += 64) {
      __syncthreads();
      for (int rr = 0; rr < 4; ++rr) {
        const int co = rr * 32 + (t >> 3);
        const int c16 = (t & 7) ^ (co & 7);
        gload_lds16(W2 + (size_t)(co0 + co) * Cin2 + ci0 + c16 * 8,
                    (char*)wT + (rr * 256 + t) * 16);
      }
      for (int rr = 0; rr < 4; ++rr) {
        const int r = rr * 32 + (t >> 3);
        const int lp = l0 + 1 + r;
        const int c16 = (t & 7) ^ (r & 7);
        gload_lds16(X2 + ((size_t)b * 1026 + lp) * Cin2 + ci0 + c16 * 8,
                    (char*)xT + (rr * 256 + t) * 16);
      }
      __syncthreads();
#pragma unroll
      for (int ks = 0; ks < 2; ++ks) {
        short8 af[4], bfr[4];
#pragma unroll
        for (int mf = 0; mf < 4; ++mf) {
          const int row = m0 + mf * 16 + (lane & 15);
          const int u = row * 8 + ((ks * 4 + (lane >> 4)) ^ (row & 7));
          af[mf] = *(const short8*)(wT + u * 8);
        }
#pragma unroll
        for (int nf = 0; nf < 4; ++nf) {
          const int r = n0 + nf * 16 + (lane & 15);
          const int u = r * 8 + ((ks * 4 + (lane >> 4)) ^ (r & 7));
          bfr[nf] = *(const short8*)(xT + u * 8);
        }
#pragma unroll
        for (int mf = 0; mf < 4; ++mf)
#pragma unroll
          for (int nf = 0; nf < 4; ++nf)
            acc[mf][nf] = __builtin_amdgcn_mfma_f32_16x16x32_bf16(
                af[mf], bfr[nf], acc[mf][nf], 0, 0, 0);
      }
    }
  }
  if (TROUT) {
    __syncthreads();
    unsigned short* TP = smem;
    float2* sr = (float2*)(TP + 128 * 128);
    float sg[4] = {}, ssg[4] = {};
#pragma unroll
    for (int mf = 0; mf < 4; ++mf)
#pragma unroll
      for (int r = 0; r < 4; ++r) {
        const int mloc = m0 + mf * 16 + (lane >> 4) * 4 + r;
        const float bv = bias[co0 + mloc];
#pragma unroll
        for (int nf = 0; nf < 4; ++nf) {
          const int l = n0 + nf * 16 + (lane & 15);
          const float v = acc[mf][nf][r] + bv;
          sg[mf] += v; ssg[mf] += v * v;
          const int u = l * 16 + ((mloc >> 3) ^ (l & 7));
          TP[u * 8 + (mloc & 7)] = f2bf(v);
        }
      }
#pragma unroll
    for (int mf = 0; mf < 4; ++mf) {
      float s = sg[mf], ss = ssg[mf];
#pragma unroll
      for (int off = 32; off; off >>= 1) {
        s += __shfl_down(s, off);
        ss += __shfl_down(ss, off);
      }
      if (lane == 0)
        sr[(((w >> 1) * 4 + mf) << 1) | (w & 1)] = make_float2(s, ss);
    }
    __syncthreads();
    for (int it = 0; it < 8; ++it) {
      const int idx = it * 256 + t;
      const int l = idx >> 4, mu = idx & 15;
      const short8 v = *(const short8*)(TP + (l * 16 + (mu ^ (l & 7))) * 8);
      *(short8*)(qd + ((size_t)b * 1026 + l0 + l + 1) * 512 + co0 + mu * 8) = v;
    }
    if (t < 8) {
      const float2 a = sr[t * 2], c = sr[t * 2 + 1];
      part[(((size_t)b * 4 + blockIdx.y) * 8 + t) * 8 + blockIdx.x] =
          make_float2(a.x + c.x, a.y + c.y);
    }
  } else if (!SCATTER) {
    float sg[4] = {}, ssg[4] = {};
#pragma unroll
    for (int mf = 0; mf < 4; ++mf) {
#pragma unroll
      for (int r = 0; r < 4; ++r) {
        const int co = co0 + m0 + mf * 16 + (lane >> 4) * 4 + r;
        float bv = bias[co];
        if (FUSE) bv += bias2[co];
#pragma unroll
        for (int nf = 0; nf < 4; ++nf) {
          const int l = l0 + n0 + nf * 16 + (lane & 15);
          const size_t o = ((size_t)b * Cout + co) * 1024 + l;
          float v = acc[mf][nf][r] + bv;
          if (ADD) {
            if (ADD16) v += bf2f(((const unsigned short*)addsrc)[o]);
            else       v += addsrc[o];
          }
          if (OUT16) ((unsigned short*)outp)[o] = f2bf(v);
          else       outp[o] = v;
          if (STATS) { sg[mf] += v; ssg[mf] += v * v; }
        }
      }
    }
    if (STATS) {
      __syncthreads();
      float2* sr = (float2*)smem;
#pragma unroll
      for (int mf = 0; mf < 4; ++mf) {
        float s = sg[mf], ss = ssg[mf];
#pragma unroll
        for (int off = 32; off; off >>= 1) {
          s += __shfl_down(s, off);
          ss += __shfl_down(ss, off);
        }
        if (lane == 0)
          sr[(((w >> 1) * 4 + mf) << 1) | (w & 1)] = make_float2(s, ss);
      }
      __syncthreads();
      if (t < 8) {
        const float2 a = sr[t * 2], c = sr[t * 2 + 1];
        part[(((size_t)b * 4 + blockIdx.y) * 8 + t) * 8 + blockIdx.x] =
            make_float2(a.x + c.x, a.y + c.y);
      }
    }
  } else {
    __syncthreads();
    unsigned short* TP = smem;
    const int sidx = co0 >> 9;            // 0=Q 1=K 2=V
    const int mbase = co0 & 511;
    const float qscale = (sidx == 0) ? 0.18033688f : 1.0f;  // 0.125*log2e
    if (sidx < 2) {
#pragma unroll
      for (int mf = 0; mf < 4; ++mf)
#pragma unroll
        for (int r = 0; r < 4; ++r) {
          const int mloc = m0 + mf * 16 + (lane >> 4) * 4 + r;
          const int mg = mbase + mloc;
          const float bv = bias[(mg >> 6) * 192 + (mg & 63) * 3 + sidx];
#pragma unroll
          for (int nf = 0; nf < 4; ++nf) {
            const int l = n0 + nf * 16 + (lane & 15);
            const int u = l * 16 + ((mloc >> 3) ^ (l & 7));
            TP[u * 8 + (mloc & 7)] = f2bf((acc[mf][nf][r] + bv) * qscale);
          }
        }
      __syncthreads();
      unsigned short* dst = (sidx == 0) ? qd : kd;
      for (int it = 0; it < 8; ++it) {
        const int idx = it * 256 + t;
        const int l = idx >> 4, mu = idx & 15;
        const int mg = mbase + mu * 8;
        const int bh = b * 8 + (mg >> 6);
        const short8 v = *(const short8*)(TP + (l * 16 + (mu ^ (l & 7))) * 8);
        *(short8*)(dst + ((size_t)bh * 1024 + l0 + l) * 64 + (mg & 63)) = v;
      }
    } else {
#pragma unroll
      for (int mf = 0; mf < 4; ++mf)
#pragma unroll
        for (int r = 0; r < 4; ++r) {
          const int mloc = m0 + mf * 16 + (lane >> 4) * 4 + r;
          const int mg = mbase + mloc;
          const float bv = bias[(mg >> 6) * 192 + (mg & 63) * 3 + 2];
#pragma unroll
          for (int nf = 0; nf < 4; ++nf) {
            const int l = n0 + nf * 16 + (lane & 15);
            const int u = mloc * 16 + ((l >> 3) ^ ((mloc & 7) << 1));
            TP[u * 8 + (l & 7)] = f2bf(acc[mf][nf][r] + bv);
          }
        }
      __syncthreads();
      for (int it = 0; it < 8; ++it) {
        const int idx = it * 256 + t;
        const int mloc = idx >> 4, lu = idx & 15;
        const int mg = mbase + mloc;
        const int bh = b * 8 + (mg >> 6);
        const short8 v =
            *(const short8*)(TP + (mloc * 16 + (lu ^ ((mloc & 7) << 1))) * 8);
        *(short8*)(vd + ((size_t)bh * 64 + (mg & 63)) * 1024 + l0 + lu * 8) = v;
      }
    }
  }
}

// ---------------- flash attention, swapped-QK^T 32x32 MFMA ----------------
// QBLK=256: 4 waves x 64 q-rows (2 i-frags each); K/V frags read once per kc
// and shared across both i-frags. 32 KB LDS, 2 blocks/CU, no online max.
__global__ __launch_bounds__(256, 2) void attn_mfma(
    const unsigned short* __restrict__ Qb, const unsigned short* __restrict__ Kb,
    const unsigned short* __restrict__ Vb, unsigned short* __restrict__ Ab) {
  __shared__ __align__(16) unsigned short Ks[2][64 * 64]; // [j][c] swz, 16 KB
  __shared__ __align__(16) unsigned short Vs[2][64 * 64]; // [c][j] swz, 16 KB
  unsigned short* QP = &Ks[0][0];   // 32 KB overlay: Q staging (256x64), O^T
  const int t = threadIdx.x, lane = t & 63, w = t >> 6;
  const int hi = lane >> 5, l31 = lane & 31;
  const int id = blockIdx.x;
  const int xcd = id & 7, local = id >> 3;     // 16 bh per XCD, 4 q-tiles each
  const int bh = (xcd << 4) | (local >> 2);
  const int b = bh >> 3, h = bh & 7;
  const int iq0 = (local & 3) * 256;
  const unsigned short* Qg = Qb + ((size_t)bh * 1024 + iq0) * 64;
  const unsigned short* Kg = Kb + (size_t)bh * 1024 * 64;
  const unsigned short* Vg = Vb + (size_t)bh * 64 * 1024;
  // ---- prologue: stage 256-row Q through the whole 32KB region ----
  for (int rr = 0; rr < 8; ++rr) {
    const int r = rr * 32 + (t >> 3), c16 = (t & 7) ^ (r & 7);
    gload_lds16(Qg + (size_t)r * 64 + c16 * 8, (char*)QP + (rr * 256 + t) * 16);
  }
  __syncthreads();
  const int irow0 = w * 64 + l31;
  const int irow1 = w * 64 + 32 + l31;
  short8 qf[2][4];
#pragma unroll
  for (int kc = 0; kc < 4; ++kc) {
    const int u0 = irow0 * 8 + ((kc * 2 + hi) ^ (irow0 & 7));
    const int u1 = irow1 * 8 + ((kc * 2 + hi) ^ (irow1 & 7));
    qf[0][kc] = *(const short8*)(QP + u0 * 8);
    qf[1][kc] = *(const short8*)(QP + u1 * 8);
  }
  __syncthreads();   // all Q reads done before K/V staging overwrites
  for (int rr = 0; rr < 2; ++rr) {
    const int r = rr * 32 + (t >> 3), c16 = (t & 7) ^ (r & 7);
    gload_lds16(Kg + (size_t)r * 64 + c16 * 8, (char*)Ks[0] + (rr * 256 + t) * 16);
    gload_lds16(Vg + (size_t)r * 1024 + c16 * 8, (char*)Vs[0] + (rr * 256 + t) * 16);
  }
  __syncthreads();
  float ls0 = 0.f, ls1 = 0.f;
  f32x16 oA[2][2] = {};   // [ifrag][cfrag]
  auto kv_iter = [&](const int ti, const int cur) {
    if (ti < 15) {
      const int j1 = (ti + 1) * 64;
      for (int rr = 0; rr < 2; ++rr) {
        const int r = rr * 32 + (t >> 3), c16 = (t & 7) ^ (r & 7);
        gload_lds16(Kg + (size_t)(j1 + r) * 64 + c16 * 8,
                    (char*)Ks[cur ^ 1] + (rr * 256 + t) * 16);
        gload_lds16(Vg + (size_t)r * 1024 + j1 + c16 * 8,
                    (char*)Vs[cur ^ 1] + (rr * 256 + t) * 16);
      }
    }
    // ---- S^T for both i-frags; K frags read once per kc ----
    f32x16 s00 = {}, s01 = {}, s10 = {}, s11 = {};   // [ifrag][jfrag]
    __builtin_amdgcn_s_setprio(1);
#pragma unroll
    for (int kc = 0; kc < 4; ++kc) {
      const int r0 = l31, r1 = 32 + l31;
      const short8 k0 = *(const short8*)(Ks[cur] + (r0 * 8 + ((kc * 2 + hi) ^ (r0 & 7))) * 8);
      const short8 k1 = *(const short8*)(Ks[cur] + (r1 * 8 + ((kc * 2 + hi) ^ (r1 & 7))) * 8);
      s00 = __builtin_amdgcn_mfma_f32_32x32x16_bf16(k0, qf[0][kc], s00, 0, 0, 0);
      s01 = __builtin_amdgcn_mfma_f32_32x32x16_bf16(k1, qf[0][kc], s01, 0, 0, 0);
      s10 = __builtin_amdgcn_mfma_f32_32x32x16_bf16(k0, qf[1][kc], s10, 0, 0, 0);
      s11 = __builtin_amdgcn_mfma_f32_32x32x16_bf16(k1, qf[1][kc], s11, 0, 0, 0);
    }
    __builtin_amdgcn_s_setprio(0);
    // ---- p = exp2(S); lane-local partial sums ----
    short8 pb0[4], pb1[4];
    {
      float p0 = 0.f, p1 = 0.f, p2 = 0.f, p3 = 0.f;
#pragma unroll
      for (int r = 0; r < 16; ++r) { s00[r] = fexp2(s00[r]); }
#pragma unroll
      for (int r = 0; r < 16; r += 4) {
        p0 += s00[r + 0]; p1 += s00[r + 1]; p2 += s00[r + 2]; p3 += s00[r + 3];
      }
#pragma unroll
      for (int r = 0; r < 16; ++r) { s01[r] = fexp2(s01[r]); }
#pragma unroll
      for (int r = 0; r < 16; r += 4) {
        p0 += s01[r + 0]; p1 += s01[r + 1]; p2 += s01[r + 2]; p3 += s01[r + 3];
      }
      ls0 += (p0 + p1) + (p2 + p3);
      pb0[0] = PACK8(s00, 0); pb0[1] = PACK8(s00, 8);
      pb0[2] = PACK8(s01, 0); pb0[3] = PACK8(s01, 8);
    }
    {
      float p0 = 0.f, p1 = 0.f, p2 = 0.f, p3 = 0.f;
#pragma unroll
      for (int r = 0; r < 16; ++r) { s10[r] = fexp2(s10[r]); }
#pragma unroll
      for (int r = 0; r < 16; r += 4) {
        p0 += s10[r + 0]; p1 += s10[r + 1]; p2 += s10[r + 2]; p3 += s10[r + 3];
      }
#pragma unroll
      for (int r = 0; r < 16; ++r) { s11[r] = fexp2(s11[r]); }
#pragma unroll
      for (int r = 0; r < 16; r += 4) {
        p0 += s11[r + 0]; p1 += s11[r + 1]; p2 += s11[r + 2]; p3 += s11[r + 3];
      }
      ls1 += (p0 + p1) + (p2 + p3);
      pb1[0] = PACK8(s10, 0); pb1[1] = PACK8(s10, 8);
      pb1[2] = PACK8(s11, 0); pb1[3] = PACK8(s11, 8);
    }
    // ---- PV: V frags read once per (cf,s), feed both i-frags ----
    __builtin_amdgcn_s_setprio(1);
#pragma unroll
    for (int cf = 0; cf < 2; ++cf) {
      const int row = cf * 32 + l31;
#pragma unroll
      for (int s = 0; s < 4; ++s) {
        const int u = row * 8 + ((s * 2 + hi) ^ (row & 7));
        const short8 va = *(const short8*)(Vs[cur] + u * 8);
        oA[0][cf] = __builtin_amdgcn_mfma_f32_32x32x16_bf16(va, pb0[s], oA[0][cf], 0, 0, 0);
        oA[1][cf] = __builtin_amdgcn_mfma_f32_32x32x16_bf16(va, pb1[s], oA[1][cf], 0, 0, 0);
      }
    }
    __builtin_amdgcn_s_setprio(0);
    __syncthreads();   // staging drained + all reads of cur done
  };
  for (int ti = 0; ti < 16; ti += 2) {
    kv_iter(ti, 0);
    kv_iter(ti + 1, 1);
  }
  // ---- finalize: per-ifrag 1/l; O^T via 32KB overlay (wave-private rows) ----
  const float inv0 = 1.f / swap_add(ls0);
  const float inv1 = 1.f / swap_add(ls1);
#pragma unroll
  for (int f = 0; f < 2; ++f) {
    const int irow = f ? irow1 : irow0;
    const float inv = f ? inv1 : inv0;
#pragma unroll
    for (int cf = 0; cf < 2; ++cf)
#pragma unroll
      for (int r = 0; r < 16; ++r) {
        const int c = cf * 32 + (r & 3) + 8 * (r >> 2) + 4 * hi;
        const int u = irow * 8 + ((c >> 3) ^ (irow & 7));
        QP[u * 8 + (c & 7)] = f2bf(oA[f][cf][r] * inv);
      }
  }
  for (int rr = 0; rr < 8; ++rr) {
    const int row = w * 64 + rr * 8 + (lane >> 3);
    const int c16 = lane & 7;
    const int u = row * 8 + (c16 ^ (row & 7));
    const short8 vv = *(const short8*)(QP + u * 8);
    *(short8*)(Ab + ((size_t)b * 1026 + iq0 + row + 1) * 512 + h * 64 + c16 * 8) = vv;
  }
}

// ---------------------------------------------------------------------------
#define MB(x) ((size_t)(x) << 20)

extern "C" void kernel_launch(void* const* d_in, const int* in_sizes, int n_in,
                              void* d_out, int out_size, void* d_ws,
                              size_t ws_size, hipStream_t stream) {
  const float* x   = (const float*)d_in[0];
  const float* n0w = (const float*)d_in[1];
  const float* n0b = (const float*)d_in[2];
  const float* c0w = (const float*)d_in[3];
  const float* c0b = (const float*)d_in[4];
  const float* n1w = (const float*)d_in[5];
  const float* n1b = (const float*)d_in[6];
  const float* c1w = (const float*)d_in[7];
  const float* c1b = (const float*)d_in[8];
  const float* skw = (const float*)d_in[9];
  const float* skb = (const float*)d_in[10];
  const float* n2w = (const float*)d_in[11];
  const float* n2b = (const float*)d_in[12];
  const float* qw  = (const float*)d_in[13];
  const float* qb  = (const float*)d_in[14];
  const float* pw  = (const float*)d_in[15];
  const float* pb  = (const float*)d_in[16];
  char* wsb = (char*)d_ws;
  unsigned short* WT0 = (unsigned short*)(wsb);            // 0.79 MB
  unsigned short* WT1 = (unsigned short*)(wsb + MB(1));    // 1.5 MB
  unsigned short* WSK = (unsigned short*)(wsb + MB(3));    // 0.26 MB
  unsigned short* WQ  = (unsigned short*)(wsb + MB(4));    // 1.5 MB
  unsigned short* WP  = (unsigned short*)(wsb + MB(6));    // 0.5 MB
  unsigned short* H2b = (unsigned short*)(wsb + MB(7));    // 16.8 MB bf16, to end
  unsigned short* Qb2 = (unsigned short*)(wsb + MB(41));   // 16 MB
  unsigned short* Kb2 = (unsigned short*)(wsb + MB(58));   // 16 MB
  unsigned short* H0t = (unsigned short*)(wsb + MB(75));   // 16 MB, dead after ntE
  unsigned short* Vb2 = (unsigned short*)(wsb + MB(75));   // 16.8 MB (reuses H0t)
  unsigned short* Xt2 = (unsigned short*)(wsb + MB(92));   // 16 MB
  unsigned short* Xt0 = (unsigned short*)(wsb + MB(109));  // 8.4 MB, dead after conv0
  unsigned short* Xt1 = (unsigned short*)(wsb + MB(109));  // 16.8 MB, dead after conv1
  unsigned short* Ab  = (unsigned short*)(wsb + MB(109));  // 16.8 MB (reuses Xt1)
  unsigned short* Xbf = (unsigned short*)(wsb + MB(126));  // 8.4 MB
  float2* MR0   = (float2*)(wsb + MB(135));                // 4 KB
  float2* PART1 = (float2*)(wsb + MB(135) + 8192);         // 16 KB
  float2* PART2 = (float2*)(wsb + MB(135) + 32768);        // 16 KB
  float* outp = (float*)d_out;

  // weight conversions + gn0 stats in one launch
  prep_stats<<<9728, 256, 0, stream>>>(c0w, c1w, skw, qw, pw,
                                       WT0, WT1, WSK, WQ, WP, x, MR0, Xt0);
  // Xt0 = silu(gn0(x)) transposed; Xbf = raw x transposed (dual output)
  nt_kernel<1, true, 256, false, true, false><<<dim3(16, 4, 16), 256, 0, stream>>>(
      x, MR0, n0w, n0b, Xt0, Xbf);
  // H0t = conv0(Xt0)  (bf16 transposed out + gn1 stats partials)
  convmm_kernel<3, false, false, false, true, true, false, false>
      <<<dim3(8, 4, 16), 256, 0, stream>>>(
      Xt0, WT0, c0b, nullptr, nullptr, H0t, nullptr, nullptr, 256, 512,
      nullptr, nullptr, nullptr, 0, PART1);
  // Xt1 = silu(gn1(H0t))  (streaming)
  ntE_kernel<<<dim3(64, 16), 256, 0, stream>>>(H0t, PART1, n1w, n1b, Xt1);
  // H2 (bf16) = conv1(Xt1) + skip(Xbf)  (fused; + gn2 stats partials)
  convmm_kernel<3, false, false, true, true, false, true, false>
      <<<dim3(8, 4, 16), 256, 0, stream>>>(
      Xt1, WT1, c1b, nullptr, (float*)H2b, nullptr, nullptr, nullptr, 512, 512,
      Xbf, WSK, skb, 256, PART2);
  // Xt2 = gn2(H2)  (bf16 input)
  nt_kernel<2, false, 512, false, false, true><<<dim3(16, 8, 16), 256, 0, stream>>>(
      (const float*)H2b, PART2, n2w, n2b, Xt2, nullptr);
  // qkv (layout-native scatter; Q pre-scaled)
  convmm_kernel<1, false, true, false, false, false, false, false>
      <<<dim3(8, 12, 16), 256, 0, stream>>>(
      Xt2, WQ, qb, nullptr, nullptr, Qb2, Kb2, Vb2, 512, 1536,
      nullptr, nullptr, nullptr, 0, nullptr);
  // a = attention(q,k,v)
  attn_mfma<<<dim3(512), 256, 0, stream>>>(Qb2, Kb2, Vb2, Ab);
  // out = h + proj(a)  (bf16 residual read)
  convmm_kernel<1, true, false, false, false, false, false, true>
      <<<dim3(8, 4, 16), 256, 0, stream>>>(
      Ab, WP, pb, (const float*)H2b, outp, nullptr, nullptr, nullptr, 512, 512,
      nullptr, nullptr, nullptr, 0, nullptr);
}